// Round 18
// baseline (190.251 us; speedup 1.0000x reference)
//
#include <hip/hip_runtime.h>
#include <cstdint>
#include <math.h>

typedef _Float16 f16;
typedef _Float16 f16x2 __attribute__((ext_vector_type(2)));
typedef _Float16 f16x4 __attribute__((ext_vector_type(4)));
typedef _Float16 f16x8 __attribute__((ext_vector_type(8)));
typedef __fp16   h16x2 __attribute__((ext_vector_type(2)));
typedef float    f32x4 __attribute__((ext_vector_type(4)));

__device__ __forceinline__ f32x4 mfma16(f16x8 a, f16x8 b, f32x4 c) {
  return __builtin_amdgcn_mfma_f32_16x16x32_f16(a, b, c, 0, 0, 0);
}
__device__ __forceinline__ float fexp2(float x) { return __builtin_amdgcn_exp2f(x); }
__device__ __forceinline__ f16x2 pkrtz(float a, float b) {
  h16x2 r = __builtin_amdgcn_cvt_pkrtz(a, b);
  return __builtin_bit_cast(f16x2, r);
}
__device__ __forceinline__ f16x8 cvt8(f32x4 a, f32x4 b) {  // RTN casts, same as old cvt
  f16x8 h;
  h[0] = (f16)a[0]; h[1] = (f16)a[1]; h[2] = (f16)a[2]; h[3] = (f16)a[3];
  h[4] = (f16)b[0]; h[5] = (f16)b[1]; h[6] = (f16)b[2]; h[7] = (f16)b[3];
  return h;
}

// ---------------- QKV GEMM: 128x128, BK=32, reg-staged, fp32 inputs -------
// R18: cvt kernel DELETED. Reg-staged path (R16) loads x/Wq/Wk/Wv fp32 and
// converts to f16 in swrite (same RTN cast as cvt -> bit-identical LDS
// contents). Weights need no transpose (y = x W^T: B[n][k] = W[n][k], both
// row-major); each 128-row B-slab is within ONE weight matrix (tile_n
// multiple of 128, boundaries at 1024) -> block-uniform pointer select.
// Q AND V written transposed [bh][d][s] with packed f16x4 stores.
__global__ __launch_bounds__(256) void gemm_qkv(
    const float* __restrict__ X,
    const float* __restrict__ Wq, const float* __restrict__ Wk, const float* __restrict__ Wv,
    const float* __restrict__ bias0, const float* __restrict__ bias1, const float* __restrict__ bias2,
    f16* __restrict__ Qtp, f16* __restrict__ Kp, f16* __restrict__ Vtp)
{
  constexpr int K = 1024;
  __shared__ __align__(16) f16 As[2][128 * 32];
  __shared__ __align__(16) f16 Bs[2][128 * 32];
  const int tid  = threadIdx.x;
  const int wave = tid >> 6, lane = tid & 63;
  const int quad = lane >> 4, col = lane & 15;
  const int tile_m = blockIdx.y * 128, tile_n = blockIdx.x * 128;
  const int mb = (wave >> 1) * 64, nb = (wave & 1) * 64;
  const int srow = lane >> 2, scol = (lane & 3) * 8;
  const float* WB = (tile_n < 1024) ? Wq : (tile_n < 2048) ? Wk : Wv;
  const float* gA = X  + (size_t)(tile_m + wave * 32 + srow) * K + scol;
  const float* gB = WB + (size_t)((tile_n & 1023) + wave * 32 + srow) * K + scol;
  const int lo = wave * 1024 + srow * 32 + scol;   // lane-linear LDS slot

  f32x4 ra0[2], ra1[2], rb0[2], rb1[2];     // fp32 register staging
  auto gload = [&](int k0) {
    ra0[0] = *(const f32x4*)(gA + k0);          ra0[1] = *(const f32x4*)(gA + k0 + 4);
    ra1[0] = *(const f32x4*)(gA + 16 * K + k0); ra1[1] = *(const f32x4*)(gA + 16 * K + k0 + 4);
    rb0[0] = *(const f32x4*)(gB + k0);          rb0[1] = *(const f32x4*)(gB + k0 + 4);
    rb1[0] = *(const f32x4*)(gB + 16 * K + k0); rb1[1] = *(const f32x4*)(gB + 16 * K + k0 + 4);
  };
  auto swrite = [&](int buf) {
    *(f16x8*)&As[buf][lo]       = cvt8(ra0[0], ra0[1]);
    *(f16x8*)&As[buf][lo + 512] = cvt8(ra1[0], ra1[1]);
    *(f16x8*)&Bs[buf][lo]       = cvt8(rb0[0], rb0[1]);
    *(f16x8*)&Bs[buf][lo + 512] = cvt8(rb1[0], rb1[1]);
  };

  f32x4 acc[4][4] = {};
  gload(0);
  swrite(0);
  gload(32);
  for (int k0 = 0; k0 < K; k0 += 32) {
    const int cur = (k0 >> 5) & 1;
    __syncthreads();                     // buf[cur] staged (lgkm drained)
    if (k0 + 32 < K) {
      swrite(cur ^ 1);                   // regs from prev iter; full-iter vmcnt cover
      if (k0 + 64 < K) gload(k0 + 64);   // refill regs, 2 iterations ahead
    }
    f16x8 af[4], bf[4];
    #pragma unroll
    for (int i = 0; i < 4; ++i)
      af[i] = *(const f16x8*)&As[cur][(mb + i * 16 + col) * 32 + quad * 8];
    #pragma unroll
    for (int j = 0; j < 4; ++j)
      bf[j] = *(const f16x8*)&Bs[cur][(nb + j * 16 + col) * 32 + quad * 8];
    #pragma unroll
    for (int i = 0; i < 4; ++i)
      #pragma unroll
      for (int j = 0; j < 4; ++j)
        acc[i][j] = mfma16(af[i], bf[j], acc[i][j]);
  }

  #pragma unroll
  for (int j = 0; j < 4; ++j) {
    const int gn = tile_n + nb + j * 16 + col;
    const int which = gn >> 10;
    const int d = gn & 1023;
    const int h = d >> 6, hi = d & 63;
    if (which != 1) {
      // Q/V -> transposed [bb][h][hi][s], packed f16x4 along s
      const float* bp = (which == 0) ? bias0 : bias2;
      f16* dst        = (which == 0) ? Qtp  : Vtp;
      const float bvv = bp[d];
      const float qs  = (which == 0) ? 0.18033688f : 1.0f;  // 1/sqrt(64)*log2(e) in Q
      #pragma unroll
      for (int i = 0; i < 4; ++i) {
        const int gm = tile_m + mb + i * 16 + quad * 4;   // r=0; s run of 4
        const int bb = gm >> 11, s = gm & 2047;
        f16x4 pw;
        #pragma unroll
        for (int r = 0; r < 4; ++r) pw[r] = (f16)((acc[i][j][r] + bvv) * qs);
        *(f16x4*)&dst[(((size_t)bb * 16 + h) * 64 + hi) * 2048 + s] = pw;
      }
    } else {
      const float bvv = bias1[d];
      #pragma unroll
      for (int i = 0; i < 4; ++i) {
        #pragma unroll
        for (int r = 0; r < 4; ++r) {
          const int gm = tile_m + mb + i * 16 + quad * 4 + r;
          const int bb = gm >> 11, s = gm & 2047;
          Kp[(((size_t)bb * 16 + h) * 2048 + s) * 64 + hi] = (f16)(acc[i][j][r] + bvv);
        }
      }
    }
  }
}

// ---------------- flash attention, merged tile-pair, static-max softmax ----
// Unchanged from R15-R17 (l-via-MFMA).
__global__ __launch_bounds__(256, 4) void attn_kernel(
    const f16* __restrict__ Qt, const f16* __restrict__ K, const f16* __restrict__ Vt,
    f16* __restrict__ ctx)
{
  __shared__ __align__(16) f16 Ks[2][64 * 72];     // [buf][kv][d], pad 72
  __shared__ __align__(16) f16 Vts[2][64 * 72];    // [buf][d][kv], pad 72
  __shared__ __align__(16) f16 Ps[4][2][16 * 72];  // per-wave, per-tile P

  const int bh  = blockIdx.x;                      // x = bh -> XCD = bh%8 (R6)
  const int yy  = blockIdx.y;
  const int p   = (yy < 8) ? yy : 23 - yy;         // CU pair (yy,yy+8): p+p'=15
  const int qlong = 31 - p, qshort = p;
  const int tid = threadIdx.x;
  const int wave = tid >> 6, lane = tid & 63;
  const int quad = lane >> 4, col = lane & 15;
  const int b = bh >> 4, h = bh & 15;
  const size_t base = (size_t)bh * 2048 * 64;
  const size_t vtb  = (size_t)bh * 64 * 2048;      // also Qt base stride

  // staging map: 512 16B-chunks per tensor, 2 per thread
  int srow[2], sc8[2];
  #pragma unroll
  for (int i = 0; i < 2; ++i) {
    const int flat = tid + i * 256;
    srow[i] = flat >> 3;
    sc8[i]  = (flat & 7) * 8;
  }

  const int qa = qlong * 64 + wave * 16;    // long tile rows (always active)
  const int qb = qshort * 64 + wave * 16;   // short tile rows (active t<=qshort)
  // Q fragments from transposed layout: element j at d = (quad*8+j), s = q
  f16x8 bqa0, bqa1, bqb0, bqb1;
  #pragma unroll
  for (int j = 0; j < 8; ++j) {
    const size_t r0 = vtb + (size_t)(quad * 8 + j) * 2048;
    const size_t r1 = vtb + (size_t)(32 + quad * 8 + j) * 2048;
    bqa0[j] = Qt[r0 + qa + col];
    bqa1[j] = Qt[r1 + qa + col];
    bqb0[j] = Qt[r0 + qb + col];
    bqb1[j] = Qt[r1 + qb + col];
  }

  // all-ones B-operand for the l-column MFMA
  f16x8 ones8;
  #pragma unroll
  for (int j = 0; j < 8; ++j) ones8[j] = (f16)1.f;

  f32x4 cta[4] = {}, ctb[4] = {};
  f32x4 zla = {}, zlb = {};                 // l accumulators (per-lane, no shuffles)

  f16x8 kr[2], vr[2];
  auto gload = [&](int t) {
    #pragma unroll
    for (int i = 0; i < 2; ++i) {
      kr[i] = *(const f16x8*)&K[base + (size_t)(t * 64 + srow[i]) * 64 + sc8[i]];
      vr[i] = *(const f16x8*)&Vt[vtb + (size_t)srow[i] * 2048 + t * 64 + sc8[i]];
    }
  };
  auto swrite = [&](int buf) {
    #pragma unroll
    for (int i = 0; i < 2; ++i) {
      *(f16x8*)&Ks[buf][srow[i] * 72 + sc8[i]]  = kr[i];
      *(f16x8*)&Vts[buf][srow[i] * 72 + sc8[i]] = vr[i];
    }
  };

  const int nIter = qlong + 1;               // 17..32

  // prologue: stage tile 0 into buf0, prefetch tile 1 into regs
  gload(0);
  __syncthreads();
  swrite(0);
  gload(1);                                  // nIter >= 17 always

  for (int t = 0; t < nIter; ++t) {
    const int cur = t & 1;
    __syncthreads();                         // buf[cur] staged; swrites drained
    const bool doB = (t <= qshort);

    // S^T = K Q^T for both tiles; ak frags shared from registers
    f32x4 sa[4], sb[4];
    __builtin_amdgcn_s_setprio(1);
    #pragma unroll
    for (int jt = 0; jt < 4; ++jt) {
      const int kro = (jt * 16 + col) * 72;
      const f16x8 ak0 = *(const f16x8*)&Ks[cur][kro + quad * 8];
      const f16x8 ak1 = *(const f16x8*)&Ks[cur][kro + 32 + quad * 8];
      f32x4 za = {};
      za = mfma16(ak0, bqa0, za);
      sa[jt] = mfma16(ak1, bqa1, za);
      if (doB) {
        f32x4 zb = {};
        zb = mfma16(ak0, bqb0, zb);
        sb[jt] = mfma16(ak1, bqb1, zb);
      }
    }
    __builtin_amdgcn_s_setprio(0);

    if (t == qlong) {   // long tile diagonal (last iteration)
      #pragma unroll
      for (int jt = 0; jt < 4; ++jt) {
        const int kg = t * 64 + jt * 16 + quad * 4;
        #pragma unroll
        for (int r = 0; r < 4; ++r)
          if (kg + r > qa + col) sa[jt][r] = -1e30f;
      }
    }
    if (t == qshort) {  // short tile diagonal
      #pragma unroll
      for (int jt = 0; jt < 4; ++jt) {
        const int kg = t * 64 + jt * 16 + quad * 4;
        #pragma unroll
        for (int r = 0; r < 4; ++r)
          if (kg + r > qb + col) sb[jt][r] = -1e30f;
      }
    }

    // ---- P = exp2(s) (static-max), long tile -> Ps slot 0 ----
    #pragma unroll
    for (int jt = 0; jt < 4; ++jt) {
      const f16x2 a01 = pkrtz(fexp2(sa[jt][0]), fexp2(sa[jt][1]));
      const f16x2 a23 = pkrtz(fexp2(sa[jt][2]), fexp2(sa[jt][3]));
      f16x4 pw; pw[0] = a01[0]; pw[1] = a01[1]; pw[2] = a23[0]; pw[3] = a23[1];
      *(f16x4*)&Ps[wave][0][col * 72 + jt * 16 + quad * 4] = pw;
    }

    // ---- P = exp2(s), short tile -> Ps slot 1 ----
    if (doB) {
      #pragma unroll
      for (int jt = 0; jt < 4; ++jt) {
        const f16x2 a01 = pkrtz(fexp2(sb[jt][0]), fexp2(sb[jt][1]));
        const f16x2 a23 = pkrtz(fexp2(sb[jt][2]), fexp2(sb[jt][3]));
        f16x4 pw; pw[0] = a01[0]; pw[1] = a01[1]; pw[2] = a23[0]; pw[3] = a23[1];
        *(f16x4*)&Ps[wave][1][col * 72 + jt * 16 + quad * 4] = pw;
      }
    }

    __asm__ volatile("s_waitcnt lgkmcnt(0)" ::: "memory");  // P RAW drain (no swrites in queue)

    // P fragments for PV + l
    const f16x8 apa0 = *(const f16x8*)&Ps[wave][0][col * 72 + quad * 8];
    const f16x8 apa1 = *(const f16x8*)&Ps[wave][0][col * 72 + 32 + quad * 8];

    // stage next tile + refill regs here: ds_writes overlap the PV phase,
    // drained by the next top-of-loop __syncthreads
    if (t + 1 < nIter) {
      swrite(cur ^ 1);
      if (t + 2 < nIter) gload(t + 2);
    }

    // ---- ctx += P V ; l += P @ 1 (matrix pipe) ----
    __builtin_amdgcn_s_setprio(1);
    zla = mfma16(apa1, ones8, mfma16(apa0, ones8, zla));
    if (doB) {
      const f16x8 apb0 = *(const f16x8*)&Ps[wave][1][col * 72 + quad * 8];
      const f16x8 apb1 = *(const f16x8*)&Ps[wave][1][col * 72 + 32 + quad * 8];
      zlb = mfma16(apb1, ones8, mfma16(apb0, ones8, zlb));
      #pragma unroll
      for (int jd = 0; jd < 4; ++jd) {
        const int vro = (jd * 16 + col) * 72;
        const f16x8 bv0 = *(const f16x8*)&Vts[cur][vro + quad * 8];
        const f16x8 bv1 = *(const f16x8*)&Vts[cur][vro + 32 + quad * 8];
        cta[jd] = mfma16(apa1, bv1, mfma16(apa0, bv0, cta[jd]));
        ctb[jd] = mfma16(apb1, bv1, mfma16(apb0, bv0, ctb[jd]));
      }
    } else {
      #pragma unroll
      for (int jd = 0; jd < 4; ++jd) {
        const int vro = (jd * 16 + col) * 72;
        const f16x8 bv0 = *(const f16x8*)&Vts[cur][vro + quad * 8];
        const f16x8 bv1 = *(const f16x8*)&Vts[cur][vro + 32 + quad * 8];
        cta[jd] = mfma16(apa1, bv1, mfma16(apa0, bv0, cta[jd]));
      }
    }
    __builtin_amdgcn_s_setprio(0);
  }

  // ---- epilogue: zl[r] = l[q=quad*4+r] directly (no shuffles) ----
  #pragma unroll
  for (int jd = 0; jd < 4; ++jd) {
    #pragma unroll
    for (int r = 0; r < 4; ++r) {
      const int qga = qa + quad * 4 + r;
      const int qgb = qb + quad * 4 + r;
      const int d = h * 64 + jd * 16 + col;
      ctx[((size_t)b * 2048 + qga) * 1024 + d] = (f16)(cta[jd][r] / zla[r]);
      ctx[((size_t)b * 2048 + qgb) * 1024 + d] = (f16)(ctb[jd][r] / zlb[r]);
    }
  }
}

// ---------------- O projection: 128x64, BK=64, reg-staged, fp32 B ---------
// R18: B (Wo) read fp32 directly, converted in swrite (cvt deleted).
// A (ctx) stays f16. Same proven reg-staging pipeline as R17.
__global__ __launch_bounds__(256) void gemm_o(
    const f16* __restrict__ A, const float* __restrict__ Wo, const float* __restrict__ bias,
    float* __restrict__ Out)
{
  constexpr int K = 1024;
  __shared__ __align__(16) f16 As[2][2][128 * 32];   // [buf][ks][row][32]
  __shared__ __align__(16) f16 Bs[2][2][64 * 32];    // [buf][ks][row][32]
  const int tid  = threadIdx.x;
  const int wave = tid >> 6, lane = tid & 63;
  const int quad = lane >> 4, col = lane & 15;
  const int tile_m = blockIdx.y * 128, tile_n = blockIdx.x * 64;
  const int mb = wave * 32;
  const int srow = lane >> 2, scol = (lane & 3) * 8;   // 16 rows x 32 cols per call
  const f16*   gA = A  + (size_t)(tile_m + srow) * K + scol;
  const float* gB = Wo + (size_t)(tile_n + srow) * K + scol;
  const int loA = srow * 32 + scol;                    // lane offset within a 16-row slab
  const int loB = (wave * 16 + srow) * 32 + scol;

  f16x8 ra[2][2];
  f32x4 rb[2][2];                           // [ks][half] fp32 B staging
  auto gload = [&](int k0) {
    #pragma unroll
    for (int ks = 0; ks < 2; ++ks) {
      #pragma unroll
      for (int i = 0; i < 2; ++i)
        ra[ks][i] = *(const f16x8*)(gA + (size_t)(wave * 32 + i * 16) * K + k0 + ks * 32);
      rb[ks][0] = *(const f32x4*)(gB + (size_t)(wave * 16) * K + k0 + ks * 32);
      rb[ks][1] = *(const f32x4*)(gB + (size_t)(wave * 16) * K + k0 + ks * 32 + 4);
    }
  };
  auto swrite = [&](int buf) {
    #pragma unroll
    for (int ks = 0; ks < 2; ++ks) {
      #pragma unroll
      for (int i = 0; i < 2; ++i)
        *(f16x8*)&As[buf][ks][(wave * 32 + i * 16) * 32 + loA] = ra[ks][i];
      *(f16x8*)&Bs[buf][ks][loB] = cvt8(rb[ks][0], rb[ks][1]);
    }
  };

  f32x4 acc[2][4] = {};
  gload(0);
  swrite(0);
  gload(64);
  for (int k0 = 0; k0 < K; k0 += 64) {
    const int cur = (k0 >> 6) & 1;
    __syncthreads();                     // buf[cur] staged (lgkm drained)
    if (k0 + 64 < K) {
      swrite(cur ^ 1);                   // regs from prev iter; full-iter vmcnt cover
      if (k0 + 128 < K) gload(k0 + 128); // refill regs, 2 iterations ahead
    }
    #pragma unroll
    for (int ks = 0; ks < 2; ++ks) {
      f16x8 af[2], bf[4];
      #pragma unroll
      for (int i = 0; i < 2; ++i)
        af[i] = *(const f16x8*)&As[cur][ks][(mb + i * 16 + col) * 32 + quad * 8];
      #pragma unroll
      for (int j = 0; j < 4; ++j)
        bf[j] = *(const f16x8*)&Bs[cur][ks][(j * 16 + col) * 32 + quad * 8];
      #pragma unroll
      for (int i = 0; i < 2; ++i)
        #pragma unroll
        for (int j = 0; j < 4; ++j)
          acc[i][j] = mfma16(af[i], bf[j], acc[i][j]);
    }
  }

  #pragma unroll
  for (int j = 0; j < 4; ++j) {
    const int gn = tile_n + j * 16 + col;
    const float bvv = bias[gn];
    #pragma unroll
    for (int i = 0; i < 2; ++i) {
      #pragma unroll
      for (int r = 0; r < 4; ++r) {
        const int gm = tile_m + mb + i * 16 + quad * 4 + r;
        Out[(size_t)gm * 1024 + gn] = acc[i][j][r] + bvv;
      }
    }
  }
}

extern "C" void kernel_launch(void* const* d_in, const int* in_sizes, int n_in,
                              void* d_out, int out_size, void* d_ws, size_t ws_size,
                              hipStream_t stream)
{
  const float* x  = (const float*)d_in[0];
  const float* Wq = (const float*)d_in[1];
  const float* bq = (const float*)d_in[2];
  const float* Wk = (const float*)d_in[3];
  const float* bk = (const float*)d_in[4];
  const float* Wv = (const float*)d_in[5];
  const float* bv = (const float*)d_in[6];
  const float* Wo = (const float*)d_in[7];
  const float* bo = (const float*)d_in[8];
  float* out = (float*)d_out;

  f16* ws = (f16*)d_ws;
  const size_t M1 = 1048576;
  f16* Qth   = ws + 8  * M1;   // 4M  [B,H,64,S] transposed, pre-scaled
  f16* Kh    = ws + 12 * M1;   // 4M  [B,H,S,64]
  f16* Vth   = ws + 20 * M1;   // 4M  [B,H,64,S] (written directly by gemm_qkv)
  f16* ctxh  = ws + 24 * M1;   // 4M  [B,S,D]

  gemm_qkv<<<dim3(24, 32), 256, 0, stream>>>(x, Wq, Wk, Wv, bq, bk, bv, Qth, Kh, Vth);
  attn_kernel<<<dim3(32, 16), 256, 0, stream>>>(Qth, Kh, Vth, ctxh);
  gemm_o<<<dim3(16, 32), 256, 0, stream>>>(ctxh, Wo, bo, out);
}